// Round 1
// baseline (397.911 us; speedup 1.0000x reference)
//
#include <hip/hip_runtime.h>
#include <math.h>

#define N_NODES 15000
#define N_EDGES 300000
#define N_RADIAL 8
#define N_SPEC 16
#define NCH 128
#define NY 9
#define RHO_STRIDE 1152   // NY*NCH
#define OUT_COLS 528      // 16 + 128 + 3*128
#define EPB 64            // edges per block
#define NBATCH 8          // nodes per block in node kernel

// ---------------- edge scatter kernel ----------------
// 128 threads = one channel b = n*16+s each. Sorted edge_src -> register
// accumulate, flush with atomics on segment change.
__global__ __launch_bounds__(128) void edge_kernel(
    const float* __restrict__ dist, const float* __restrict__ vec,
    const float* __restrict__ sw,   const float* __restrict__ stab,
    const int* __restrict__ species, const int* __restrict__ esrc,
    const int* __restrict__ edst,   float* __restrict__ rhoi)
{
    const int t = threadIdx.x;          // b in [0,128)
    const int n = t >> 4;               // radial index 0..7
    const int s = t & 15;               // species-feature index 0..15
    const float coefn = (float)(n + 1) * (3.14159265358979323846f / 5.0f);
    const float bnorm = 0.6324555320336759f;   // sqrt(2/cutoff)
    const float s3  = 1.7320508075688772f;
    const float s5  = 2.2360679774997896f;
    const float s15 = 3.872983346207417f;

    int e0 = blockIdx.x * EPB;
    if (e0 >= N_EDGES) return;
    int e1 = min(e0 + EPB, N_EDGES);

    float acc[NY];
    #pragma unroll
    for (int m = 0; m < NY; ++m) acc[m] = 0.0f;

    int cur = esrc[e0];
    for (int e = e0; e < e1; ++e) {
        int src = esrc[e];
        if (src != cur) {   // uniform across block -> no divergence
            float* base = rhoi + (size_t)cur * RHO_STRIDE + t;
            #pragma unroll
            for (int m = 0; m < NY; ++m) {
                atomicAdd(base + m * NCH, acc[m]);
                acc[m] = 0.0f;
            }
            cur = src;
        }
        float r    = dist[e];
        float invr = 1.0f / r;
        float swv  = sw[e];
        float x = vec[3*e+0] * invr;
        float y = vec[3*e+1] * invr;
        float z = vec[3*e+2] * invr;
        int   sp = species[edst[e]];
        float sv = stab[sp * N_SPEC + s];
        float D  = bnorm * __sinf(coefn * r) * invr * swv * sv;

        acc[0] += D;
        acc[1] += D * (s3 * x);
        acc[2] += D * (s3 * y);
        acc[3] += D * (s3 * z);
        acc[4] += D * (s15 * x * y);
        acc[5] += D * (s15 * y * z);
        acc[6] += D * (0.5f * s5 * (3.0f * z * z - 1.0f));
        acc[7] += D * (s15 * x * z);
        acc[8] += D * (0.5f * s15 * (x * x - y * y));
    }
    float* base = rhoi + (size_t)cur * RHO_STRIDE + t;
    #pragma unroll
    for (int m = 0; m < NY; ++m) atomicAdd(base + m * NCH, acc[m]);
}

// ---------------- node kernel ----------------
// 128 threads = one output column pair (c, c+128). NBATCH nodes per block,
// rho staged in LDS as [m*128+b][nb] so the per-b nb-reads are contiguous.
__global__ __launch_bounds__(128) void node_kernel(
    const float* __restrict__ stab, const int* __restrict__ species,
    const float* __restrict__ W0,   const float* __restrict__ W1,
    const float* __restrict__ W2,   const float* __restrict__ rhoi,
    float* __restrict__ out)
{
    __shared__ float srho[NY * NCH * NBATCH];   // 36.9 KB
    const int t = threadIdx.x;                  // column c in [0,128)
    const int node0 = blockIdx.x * NBATCH;

    // Stage rho (coalesced global read, strided LDS write)
    for (int nb = 0; nb < NBATCH; ++nb) {
        const float* src = rhoi + (size_t)(node0 + nb) * RHO_STRIDE;
        for (int j = t; j < RHO_STRIDE; j += 128)
            srho[j * NBATCH + nb] = src[j];
    }
    __syncthreads();

    // Head: senc (16 cols) + rhoi[:,0,:] (128 cols)
    #pragma unroll
    for (int nb = 0; nb < NBATCH; ++nb) {
        int node = node0 + nb;
        float* o = out + (size_t)node * OUT_COLS;
        if (t < N_SPEC) o[t] = stab[species[node] * N_SPEC + t];
        o[16 + t] = srho[t * NBATCH + nb];
    }

    const float* Ws[3] = {W0, W1, W2};
    const float scl[3] = {1.0f, 0.5773502691896258f, 0.4472135954999579f};

    for (int l = 0; l < 3; ++l) {
        const float* __restrict__ W = Ws[l];
        float xi[NBATCH];
        #pragma unroll
        for (int nb = 0; nb < NBATCH; ++nb) xi[nb] = 0.0f;

        for (int m = l * l; m < (l + 1) * (l + 1); ++m) {
            float accA[NBATCH], accB[NBATCH];
            #pragma unroll
            for (int nb = 0; nb < NBATCH; ++nb) { accA[nb] = 0.0f; accB[nb] = 0.0f; }

            const float* rbase = &srho[m * NCH * NBATCH];
            for (int b = 0; b < NCH; ++b) {
                float w1 = W[b * 256 + t];
                float w2 = W[b * 256 + t + 128];
                const float* rp = rbase + b * NBATCH;
                #pragma unroll
                for (int nb = 0; nb < NBATCH; ++nb) {
                    float rv = rp[nb];
                    accA[nb] += rv * w1;
                    accB[nb] += rv * w2;
                }
            }
            #pragma unroll
            for (int nb = 0; nb < NBATCH; ++nb) xi[nb] += accA[nb] * accB[nb];
        }
        #pragma unroll
        for (int nb = 0; nb < NBATCH; ++nb)
            out[(size_t)(node0 + nb) * OUT_COLS + 144 + l * NCH + t] = xi[nb] * scl[l];
    }
}

extern "C" void kernel_launch(void* const* d_in, const int* in_sizes, int n_in,
                              void* d_out, int out_size, void* d_ws, size_t ws_size,
                              hipStream_t stream) {
    const float* distances = (const float*)d_in[0];
    const float* vec       = (const float*)d_in[1];
    const float* sw        = (const float*)d_in[2];
    const float* stab      = (const float*)d_in[3];
    const float* W0        = (const float*)d_in[4];
    const float* W1        = (const float*)d_in[5];
    const float* W2        = (const float*)d_in[6];
    const int*   species   = (const int*)d_in[7];
    const int*   esrc      = (const int*)d_in[8];
    const int*   edst      = (const int*)d_in[9];
    float* out  = (float*)d_out;
    float* rhoi = (float*)d_ws;                       // 15000*1152 fp32 = 69.12 MB

    hipMemsetAsync(rhoi, 0, (size_t)N_NODES * RHO_STRIDE * sizeof(float), stream);

    int eblocks = (N_EDGES + EPB - 1) / EPB;
    edge_kernel<<<eblocks, 128, 0, stream>>>(distances, vec, sw, stab, species,
                                             esrc, edst, rhoi);

    int nblocks = N_NODES / NBATCH;                   // 15000/8 = 1875 exact
    node_kernel<<<nblocks, 128, 0, stream>>>(stab, species, W0, W1, W2, rhoi, out);
}